// Round 13
// baseline (473.704 us; speedup 1.0000x reference)
//
#include <hip/hip_runtime.h>
#include <hip/hip_bf16.h>

// dims
constexpr int BB = 16, IC = 512, OC = 512, HH = 64, WW = 64, HW = 64 * 64, SD = 512;
constexpr float MOD_SCALE = 0.04419417382415922f;      // 1/sqrt(512)
constexpr float CONV_SCALE = 0.014731391274719739f;    // 1/sqrt(512*9)
constexpr float CONV_SCALE2 = 2.170138888888889e-4f;   // 1/4608

typedef float f32x4 __attribute__((ext_vector_type(4)));
typedef short bf16x8 __attribute__((ext_vector_type(8)));

#define VMWAIT(n) asm volatile("s_waitcnt vmcnt(" #n ")" ::: "memory")
#define LGKM0()   asm volatile("s_waitcnt lgkmcnt(0)" ::: "memory")

__device__ __forceinline__ unsigned short f2bf(float x) {
  __hip_bfloat16 h = __float2bfloat16(x);
  return *(unsigned short*)&h;
}

// ---------------- kernel 1: s[b][ic] = style @ (mod_weight*ms)^T + mod_bias ----
__global__ void k_style(const float* __restrict__ style, const float* __restrict__ mw,
                        const float* __restrict__ mb, float* __restrict__ s) {
  __shared__ float st[SD];
  const int b = blockIdx.x;
  for (int i = threadIdx.x; i < SD; i += 256) st[i] = style[b * SD + i];
  __syncthreads();
  for (int ic = threadIdx.x; ic < IC; ic += 256) {
    const float4* wr = (const float4*)(mw + (size_t)ic * SD);
    float acc = 0.f;
    for (int d = 0; d < SD / 4; ++d) {
      float4 w4 = wr[d];
      float4 s4 = *(const float4*)&st[d * 4];
      acc += w4.x * s4.x + w4.y * s4.y + w4.z * s4.z + w4.w * s4.w;
    }
    s[b * IC + ic] = acc * MOD_SCALE + mb[ic];
  }
}

// ---------------- kernel 2: pack weights [tap][oc][ic] bf16 + w2sum[oc][ic] ----
__global__ void k_pack(const float* __restrict__ w, unsigned short* __restrict__ wpack,
                       float* __restrict__ w2sum) {
  const int oc = blockIdx.x;
  const int ic0 = threadIdx.x * 2;
  const float* p = w + (size_t)oc * IC * 9 + (size_t)ic0 * 9;
  float v[18];
#pragma unroll
  for (int i = 0; i < 18; ++i) v[i] = p[i];
  float s0 = 0.f, s1 = 0.f;
#pragma unroll
  for (int t = 0; t < 9; ++t) { s0 += v[t] * v[t]; s1 += v[9 + t] * v[9 + t]; }
  *(float2*)&w2sum[oc * IC + ic0] = make_float2(s0, s1);
#pragma unroll
  for (int t = 0; t < 9; ++t) {
    unsigned int pk = (unsigned int)f2bf(v[t]) | ((unsigned int)f2bf(v[9 + t]) << 16);
    *(unsigned int*)&wpack[((size_t)t * OC + oc) * IC + ic0] = pk;
  }
}

// ---------------- kernel 3: fscale[b][oc] = conv_scale * rsqrt(cs2*sum + eps) --
__global__ void k_demod(const float* __restrict__ s, const float* __restrict__ w2sum,
                        float* __restrict__ fscale) {
  __shared__ float s2[IC];
  const int b = blockIdx.x;
  for (int i = threadIdx.x; i < IC; i += 256) { float v = s[b * IC + i]; s2[i] = v * v; }
  __syncthreads();
  for (int oc = threadIdx.x; oc < OC; oc += 256) {
    const float4* wr = (const float4*)(w2sum + (size_t)oc * IC);
    float acc = 0.f;
    for (int i4 = 0; i4 < IC / 4; ++i4) {
      float4 w4 = wr[i4];
      float4 q4 = *(const float4*)&s2[i4 * 4];
      acc += w4.x * q4.x + w4.y * q4.y + w4.z * q4.z + w4.w * q4.w;
    }
    fscale[b * OC + oc] = CONV_SCALE * rsqrtf(CONV_SCALE2 * acc + 1e-8f);
  }
}

// A-frag read from the pair's shared buffer NB (static indices only)
#define RD_AF(DST, NB)                                                         \
  do {                                                                         \
    _Pragma("unroll") for (int i_ = 0; i_ < 4; ++i_) {                         \
      int r_ = i_ * 16 + lrow;                                                 \
      DST[i_] = *(const bf16x8*)&Apool[wm][(NB)][r_ * 32 +                     \
                                               ((lk ^ ((r_ >> 1) & 3)) * 8)];  \
    }                                                                          \
  } while (0)

// B-frag read for tap TN from Bsm buffer index BI (static indices only)
#define RD_BF(DST, TN, BI)                                                     \
  do {                                                                         \
    const int dh_ = (TN) / 3 - 1, dw_ = (TN) % 3 - 1;                          \
    _Pragma("unroll") for (int j_ = 0; j_ < 4; ++j_) {                         \
      int r_ = (wn + dh_ + 1) * 66 + j_ * 16 + lrow + dw_ + 1;                 \
      DST[j_] = *(const bf16x8*)&Bsm[(BI)][r_ * 32 +                           \
                                          ((lk ^ ((r_ >> 1) & 3)) * 8)];       \
    }                                                                          \
  } while (0)

#define MFMA16(AF, BF)                                                         \
  do {                                                                         \
    _Pragma("unroll") for (int i_ = 0; i_ < 4; ++i_)                           \
      _Pragma("unroll") for (int j_ = 0; j_ < 4; ++j_)                         \
        acc[i_][j_] = __builtin_amdgcn_mfma_f32_16x16x32_bf16(AF[i_], BF[j_],  \
                                                              acc[i_][j_], 0, 0, 0); \
  } while (0)

// ---------------- kernel 4: the conv (implicit GEMM, bf16 MFMA) ----------------
// grid 2048 = 16b x 4mblk x 32nblk (XCD-swizzled); block 256 = 4 waves (2wm x 2wn).
// r12's winning schedule (pre-barrier frag reads, wave-issued A DMA w/ own-wave
// counted vmcnt, double-buffered Bsm restaged mid-icb, 1 pacing barrier/tap,
// post-barrier chain = MFMA only) at HALF the LDS: the (wm,0)/(wm,1) wave pair
// SHARES one A buffer set, both waves issuing identical duplicate DMA (same
// bytes -> benign; own vmcnt still proves own writes = full tile). LDS 58.4 KB
// -> 2 independent blocks/CU: the 2 waves on each SIMD come from different
// blocks with unaligned phases, so LDS-read bursts overlap MFMA bursts.
__global__ __launch_bounds__(256, 2) void k_conv(
    const float* __restrict__ x, const unsigned short* __restrict__ wpack,
    const float* __restrict__ s, const float* __restrict__ fscale,
    float* __restrict__ out) {
  __shared__ __align__(128) unsigned short Apool[2][3][64 * 32];  // [wm][buf] shared per pair
  __shared__ __align__(128) unsigned short Bsm[2][264 * 32];      // double-buffered

  const int bx = ((blockIdx.x & 7) << 8) | (blockIdx.x >> 3);  // XCD swizzle
  const int b = bx >> 7, mblk = (bx >> 5) & 3, nblk = bx & 31;

  const int tid = threadIdx.x;
  const int wave = tid >> 6, lane = tid & 63;
  const int wm = wave >> 1, wn = wave & 1;
  const int lrow = lane & 15, lk = lane >> 4;
  const int h0 = nblk * 2;

  const float* xb = x + (size_t)b * IC * HW;
  const float* sb = s + b * IC;

  f32x4 acc[4][4];
#pragma unroll
  for (int i = 0; i < 4; ++i)
#pragma unroll
    for (int j = 0; j < 4; ++j) acc[i][j] = f32x4{0.f, 0.f, 0.f, 0.f};

  // zero w-halo columns of BOTH Bsm buffers (2 bufs x 4 rows x 2 sides x 32 ic)
#pragma unroll
  for (int z = 0; z < 2; ++z) {
    int q = (tid >> 5) + z * 8;            // 0..15
    int bi = q >> 3;
    int hh = (q >> 1) & 3, wz = (q & 1) ? 65 : 0;
    Bsm[bi][(hh * 66 + wz) * 32 + (tid & 31)] = 0;
  }

  // stage x tile for one 32-ic block into Bsm[bi]: [4 halo rows][64 w][32 ic] * s
  auto stageB = [&](int icb, int bi) {
    const int hh = wave;     // 0..3
    const int h_abs = h0 - 1 + hh;
    const bool vh = (h_abs >= 0) && (h_abs < HH);
    const int h_safe = vh ? h_abs : 0;
    const int r = hh * 66 + lane + 1;
    const int swz = (r >> 1) & 3;
    const float* src = xb + (size_t)(icb * 32) * HW + h_safe * WW + lane;
#pragma unroll
    for (int c = 0; c < 4; ++c) {
      unsigned int pk[4];
#pragma unroll
      for (int jj = 0; jj < 4; ++jj) {
        int ic = c * 8 + jj * 2;
        float m0 = vh ? sb[icb * 32 + ic] : 0.f;
        float m1 = vh ? sb[icb * 32 + ic + 1] : 0.f;
        pk[jj] = (unsigned int)f2bf(src[(size_t)ic * HW] * m0) |
                 ((unsigned int)f2bf(src[(size_t)(ic + 1) * HW] * m1) << 16);
      }
      *(uint4*)&Bsm[bi][r * 32 + ((c ^ swz) * 8)] = make_uint4(pk[0], pk[1], pk[2], pk[3]);
    }
  };

  // pair-shared A DMA: both waves of the wm-pair issue identical loads (4 x 1KB)
  auto issueA = [&](int tap, int icb, int nb) {
    const unsigned short* base =
        wpack + ((size_t)(tap * OC + mblk * 128 + wm * 64)) * IC + icb * 32;
    unsigned short* dst = &Apool[wm][nb][0];
#pragma unroll
    for (int q = 0; q < 4; ++q) {
      int rl = q * 16 + (lane >> 2);
      int cs = (lane & 3) ^ ((rl >> 1) & 3);
      const unsigned short* g = base + (size_t)rl * IC + cs * 8;
      __builtin_amdgcn_global_load_lds(
          (const __attribute__((address_space(1))) void*)g,
          (__attribute__((address_space(3))) void*)(dst + q * 16 * 32), 16, 0, 0);
    }
  };

  // ---- prologue ----
  stageB(0, 0);
  issueA(0, 0, 0);   // D(0) -> buf0
  issueA(1, 0, 1);   // D(1) -> buf1
  __syncthreads();   // full drain + publish Bsm[0] + halo zeros

  bf16x8 afA[4], afB[4], bfA[4], bfB[4];
  RD_AF(afA, 0);
  RD_BF(bfA, 0, 0);

  for (int e = 0; e < 16; e += 2) {   // icb pairs: everything static inside
#pragma unroll
    for (int tt = 0; tt < 18; ++tt) {
      const int t = tt % 9;           // compile-time tap
      const int io = tt / 9;          // compile-time icb offset = current Bsm index
      const int icb = e + io;
      const bool last = (e == 14) && (io == 1);
      const int P = (io + t) & 1;     // frag parity (static: e even, 18 | superblock)

      __builtin_amdgcn_s_barrier();   // pacing barrier (locality lockstep)
      __builtin_amdgcn_sched_barrier(0);

      __builtin_amdgcn_s_setprio(1);
      if (P == 0) { MFMA16(afA, bfA); } else { MFMA16(afB, bfB); }
      __builtin_amdgcn_s_setprio(0);
      __builtin_amdgcn_sched_barrier(0);

      // issue D(g+2) into buf (t+2)%3 (pair's reads of it ended at phase g-1;
      // pacing barriers order those reads before this write)
      if (!(last && t >= 7)) {
        if (t <= 6) issueA(t + 2, icb, (t + 2) % 3);
        else        issueA(t - 7, icb + 1, (t + 2) % 3);
      }

      // pre-read frags for g+1 (own-wave vmcnt proves D(g+1) landed)
      if (!(last && t == 8)) {
        if (last && t == 7) { VMWAIT(0); } else { VMWAIT(4); }
        __builtin_amdgcn_sched_barrier(0);
        if (P == 0) {
          RD_AF(afB, (t + 1) % 3);
          if (t < 8) { RD_BF(bfB, t + 1, io); }
          else       { RD_BF(bfB, 0, 1 - io); }
        } else {
          RD_AF(afA, (t + 1) % 3);
          if (t < 8) { RD_BF(bfA, t + 1, io); }
          else       { RD_BF(bfA, 0, 1 - io); }
        }
      }

      // stage next icb's B into the shadow buffer, mid-icb (hidden under taps)
      if (t == 4 && !(e == 14 && io == 1)) {
        stageB(icb + 1, 1 - io);
        LGKM0();
        __builtin_amdgcn_sched_barrier(0);
      }
    }
  }

  // epilogue: scale by conv_scale*demod[b][oc], coalesced 64B stores
  const float* fsb = fscale + b * OC;
#pragma unroll
  for (int i = 0; i < 4; ++i) {
#pragma unroll
    for (int rr = 0; rr < 4; ++rr) {
      const int oc = mblk * 128 + wm * 64 + i * 16 + lk * 4 + rr;
      const float sc = fsb[oc];
      float* orow = out + ((size_t)(b * OC + oc)) * HW + nblk * 128 + wn * 64 + lrow;
#pragma unroll
      for (int j = 0; j < 4; ++j) orow[j * 16] = acc[i][j][rr] * sc;
    }
  }
}

// ---------------- launch --------------------------------------------------------
extern "C" void kernel_launch(void* const* d_in, const int* in_sizes, int n_in,
                              void* d_out, int out_size, void* d_ws, size_t ws_size,
                              hipStream_t stream) {
  const float* input = (const float*)d_in[0];       // [16,512,64,64]
  const float* style = (const float*)d_in[1];       // [16,512]
  const float* weight = (const float*)d_in[2];      // [1,512,512,3,3]
  const float* mod_weight = (const float*)d_in[3];  // [512,512]
  const float* mod_bias = (const float*)d_in[4];    // [512]
  float* out = (float*)d_out;

  char* ws = (char*)d_ws;
  constexpr size_t WPACK_B = (size_t)9 * OC * IC * 2;   // 4,718,592
  constexpr size_t W2SUM_B = (size_t)OC * IC * 4;       // 1,048,576
  constexpr size_t S_B = (size_t)BB * IC * 4;           // 32,768
  unsigned short* wpack = (unsigned short*)ws;
  float* w2sum = (float*)(ws + WPACK_B);
  float* s = (float*)(ws + WPACK_B + W2SUM_B);
  float* fscale = (float*)(ws + WPACK_B + W2SUM_B + S_B);

  k_style<<<BB, 256, 0, stream>>>(style, mod_weight, mod_bias, s);
  k_pack<<<OC, 256, 0, stream>>>(weight, wpack, w2sum);
  k_demod<<<BB, 256, 0, stream>>>(s, w2sum, fscale);
  k_conv<<<2048, 256, 0, stream>>>(input, wpack, s, fscale, out);
}

// Round 14
// 392.542 us; speedup vs baseline: 1.2068x; 1.2068x over previous
//
#include <hip/hip_runtime.h>
#include <hip/hip_bf16.h>

// dims
constexpr int BB = 16, IC = 512, OC = 512, HH = 64, WW = 64, HW = 64 * 64, SD = 512;
constexpr float MOD_SCALE = 0.04419417382415922f;      // 1/sqrt(512)
constexpr float CONV_SCALE = 0.014731391274719739f;    // 1/sqrt(512*9)
constexpr float CONV_SCALE2 = 2.170138888888889e-4f;   // 1/4608

typedef float f32x4 __attribute__((ext_vector_type(4)));
typedef short bf16x8 __attribute__((ext_vector_type(8)));

#define VMWAIT(n) asm volatile("s_waitcnt vmcnt(" #n ")" ::: "memory")
#define LGKM0()   asm volatile("s_waitcnt lgkmcnt(0)" ::: "memory")

__device__ __forceinline__ unsigned short f2bf(float x) {
  __hip_bfloat16 h = __float2bfloat16(x);
  return *(unsigned short*)&h;
}

// ---------------- kernel 1: s[b][ic] = style @ (mod_weight*ms)^T + mod_bias ----
__global__ void k_style(const float* __restrict__ style, const float* __restrict__ mw,
                        const float* __restrict__ mb, float* __restrict__ s) {
  __shared__ float st[SD];
  const int b = blockIdx.x;
  for (int i = threadIdx.x; i < SD; i += 256) st[i] = style[b * SD + i];
  __syncthreads();
  for (int ic = threadIdx.x; ic < IC; ic += 256) {
    const float4* wr = (const float4*)(mw + (size_t)ic * SD);
    float acc = 0.f;
    for (int d = 0; d < SD / 4; ++d) {
      float4 w4 = wr[d];
      float4 s4 = *(const float4*)&st[d * 4];
      acc += w4.x * s4.x + w4.y * s4.y + w4.z * s4.z + w4.w * s4.w;
    }
    s[b * IC + ic] = acc * MOD_SCALE + mb[ic];
  }
}

// ---------------- kernel 2: pack weights [tap][oc][ic] bf16 + w2sum[oc][ic] ----
__global__ void k_pack(const float* __restrict__ w, unsigned short* __restrict__ wpack,
                       float* __restrict__ w2sum) {
  const int oc = blockIdx.x;
  const int ic0 = threadIdx.x * 2;
  const float* p = w + (size_t)oc * IC * 9 + (size_t)ic0 * 9;
  float v[18];
#pragma unroll
  for (int i = 0; i < 18; ++i) v[i] = p[i];
  float s0 = 0.f, s1 = 0.f;
#pragma unroll
  for (int t = 0; t < 9; ++t) { s0 += v[t] * v[t]; s1 += v[9 + t] * v[9 + t]; }
  *(float2*)&w2sum[oc * IC + ic0] = make_float2(s0, s1);
#pragma unroll
  for (int t = 0; t < 9; ++t) {
    unsigned int pk = (unsigned int)f2bf(v[t]) | ((unsigned int)f2bf(v[9 + t]) << 16);
    *(unsigned int*)&wpack[((size_t)t * OC + oc) * IC + ic0] = pk;
  }
}

// ---------------- kernel 3: fscale[b][oc] = conv_scale * rsqrt(cs2*sum + eps) --
__global__ void k_demod(const float* __restrict__ s, const float* __restrict__ w2sum,
                        float* __restrict__ fscale) {
  __shared__ float s2[IC];
  const int b = blockIdx.x;
  for (int i = threadIdx.x; i < IC; i += 256) { float v = s[b * IC + i]; s2[i] = v * v; }
  __syncthreads();
  for (int oc = threadIdx.x; oc < OC; oc += 256) {
    const float4* wr = (const float4*)(w2sum + (size_t)oc * IC);
    float acc = 0.f;
    for (int i4 = 0; i4 < IC / 4; ++i4) {
      float4 w4 = wr[i4];
      float4 q4 = *(const float4*)&s2[i4 * 4];
      acc += w4.x * q4.x + w4.y * q4.y + w4.z * q4.z + w4.w * q4.w;
    }
    fscale[b * OC + oc] = CONV_SCALE * rsqrtf(CONV_SCALE2 * acc + 1e-8f);
  }
}

// A-frag read from this wave's private buffer NB (static indices only)
#define RD_AF(DST, NB)                                                         \
  do {                                                                         \
    _Pragma("unroll") for (int i_ = 0; i_ < 4; ++i_) {                         \
      int r_ = i_ * 16 + lrow;                                                 \
      DST[i_] = *(const bf16x8*)&Apw[(NB) * 2048 + r_ * 32 +                   \
                                     ((lk ^ ((r_ >> 1) & 3)) * 8)];            \
    }                                                                          \
  } while (0)

// B-frag read for tap TN from Bsm buffer BSRC (static indices only)
#define RD_BF(DST, TN, BSRC)                                                   \
  do {                                                                         \
    const int dh_ = (TN) / 3 - 1, dw_ = (TN) % 3 - 1;                          \
    _Pragma("unroll") for (int j_ = 0; j_ < 4; ++j_) {                         \
      int r_ = (wn + dh_ + 1) * 66 + j_ * 16 + lrow + dw_ + 1;                 \
      DST[j_] = *(const bf16x8*)&(BSRC)[r_ * 32 + ((lk ^ ((r_ >> 1) & 3)) * 8)];\
    }                                                                          \
  } while (0)

#define MFMA16(AF, BF)                                                         \
  do {                                                                         \
    _Pragma("unroll") for (int i_ = 0; i_ < 4; ++i_)                           \
      _Pragma("unroll") for (int j_ = 0; j_ < 4; ++j_)                         \
        acc[i_][j_] = __builtin_amdgcn_mfma_f32_16x16x32_bf16(AF[i_], BF[j_],  \
                                                              acc[i_][j_], 0, 0, 0); \
  } while (0)

// ---------------- kernel 4: the conv (implicit GEMM, bf16 MFMA) ----------------
// r12 (the 400 us winner) with pacing barriers thinned 9 -> 3 per icb (t=0,3,6).
// Safety: A reuse is own-wave (vmcnt+program order); Bsm WAR/RAW are protected
// by the t==3 / t==6 barriers (stager LGKM0s at t==4, reader pre-reads at t==8).
// Drift bounded <= 3 taps -> L2 locality preserved.
__global__ __launch_bounds__(512, 2) void k_conv(
    const float* __restrict__ x, const unsigned short* __restrict__ wpack,
    const float* __restrict__ s, const float* __restrict__ fscale,
    float* __restrict__ out) {
  extern __shared__ __align__(128) unsigned short lds[];
  // layout (shorts): Apriv[8 waves][3 bufs][64*32] = 49152 ; Bsm[2][264*32] = 16896

  const int bx = ((blockIdx.x & 7) << 7) | (blockIdx.x >> 3);  // XCD swizzle
  const int b = bx >> 6, mblk = (bx >> 5) & 1, nblk = bx & 31;

  const int tid = threadIdx.x;
  const int wave = tid >> 6, lane = tid & 63;
  const int wm = wave >> 1, wn = wave & 1;
  const int lrow = lane & 15, lk = lane >> 4;
  const int h0 = nblk * 2;

  unsigned short* Apw = lds + wave * 3 * 2048;  // this wave's private A bufs
  unsigned short* Bsm0 = lds + 49152;
  unsigned short* Bsm1 = Bsm0 + 8448;

  const float* xb = x + (size_t)b * IC * HW;
  const float* sb = s + b * IC;

  f32x4 acc[4][4];
#pragma unroll
  for (int i = 0; i < 4; ++i)
#pragma unroll
    for (int j = 0; j < 4; ++j) acc[i][j] = f32x4{0.f, 0.f, 0.f, 0.f};

  // zero w-halo columns of BOTH Bsm buffers (2 bufs x 4 rows x 2 sides x 32 ic)
  {
    int q = tid >> 5;                     // 0..15
    unsigned short* B = (q >> 3) ? Bsm1 : Bsm0;
    int hh = (q >> 1) & 3, wz = (q & 1) ? 65 : 0;
    B[(hh * 66 + wz) * 32 + (tid & 31)] = 0;
  }

  // stage x tile for one 32-ic block into dst: [4 halo rows][64 w][32 ic] * s
  auto stageB = [&](int icb, unsigned short* dst) {
    const int hh = wave & 3;
    const int h_abs = h0 - 1 + hh;
    const bool vh = (h_abs >= 0) && (h_abs < HH);
    const int h_safe = vh ? h_abs : 0;
    const int r = hh * 66 + lane + 1;
    const int swz = (r >> 1) & 3;
    const float* src = xb + (size_t)(icb * 32) * HW + h_safe * WW + lane;
#pragma unroll
    for (int cc = 0; cc < 2; ++cc) {
      const int c = (wave >> 2) * 2 + cc;
      unsigned int pk[4];
#pragma unroll
      for (int jj = 0; jj < 4; ++jj) {
        int ic = c * 8 + jj * 2;
        float m0 = vh ? sb[icb * 32 + ic] : 0.f;
        float m1 = vh ? sb[icb * 32 + ic + 1] : 0.f;
        pk[jj] = (unsigned int)f2bf(src[(size_t)ic * HW] * m0) |
                 ((unsigned int)f2bf(src[(size_t)(ic + 1) * HW] * m1) << 16);
      }
      *(uint4*)&dst[r * 32 + ((c ^ swz) * 8)] = make_uint4(pk[0], pk[1], pk[2], pk[3]);
    }
  };

  // wave-private A DMA: 4 global_load_lds (1KB each) into own buffer nb
  auto issueA = [&](int tap, int icb, int nb) {
    const unsigned short* base =
        wpack + ((size_t)(tap * OC + mblk * 256 + wm * 64)) * IC + icb * 32;
    unsigned short* dst = Apw + nb * 2048;
#pragma unroll
    for (int q = 0; q < 4; ++q) {
      int rl = q * 16 + (lane >> 2);
      int cs = (lane & 3) ^ ((rl >> 1) & 3);
      const unsigned short* g = base + (size_t)rl * IC + cs * 8;
      __builtin_amdgcn_global_load_lds(
          (const __attribute__((address_space(1))) void*)g,
          (__attribute__((address_space(3))) void*)(dst + q * 16 * 32), 16, 0, 0);
    }
  };

  // ---- prologue ----
  stageB(0, Bsm0);
  issueA(0, 0, 0);   // D(0) -> buf0
  issueA(1, 0, 1);   // D(1) -> buf1
  __syncthreads();   // full drain + publish Bsm0 + halo zeros

  bf16x8 afA[4], afB[4], bfA[4], bfB[4];
  RD_AF(afA, 0);
  RD_BF(bfA, 0, Bsm0);

  for (int e = 0; e < 16; e += 2) {   // icb pairs: parity static inside
#pragma unroll
    for (int tt = 0; tt < 18; ++tt) {
      const int t = tt % 9;           // compile-time tap
      const int io = tt / 9;          // compile-time icb offset (0/1) = Bsm cur
      const int icb = e + io;
      const bool last = (e == 14) && (io == 1);
      const int P = (io + t) & 1;     // frag parity (e even -> static)

      if (t % 3 == 0) {
        __builtin_amdgcn_s_barrier();   // pacing barrier (t = 0,3,6 only)
        __builtin_amdgcn_sched_barrier(0);
      }

      __builtin_amdgcn_s_setprio(1);
      if (P == 0) { MFMA16(afA, bfA); } else { MFMA16(afB, bfB); }
      __builtin_amdgcn_s_setprio(0);
      __builtin_amdgcn_sched_barrier(0);

      // issue D(g+2) into own buf (t+2)%3 (own reads of that buf ended at g-1)
      if (!(last && t >= 7)) {
        if (t <= 6) issueA(t + 2, icb, (t + 2) % 3);
        else        issueA(t - 7, icb + 1, (t + 2) % 3);
      }

      // pre-read frags for g+1 (own-wave vmcnt proves D(g+1) landed)
      if (!(last && t == 8)) {
        if (last && t == 7) { VMWAIT(0); } else { VMWAIT(4); }
        __builtin_amdgcn_sched_barrier(0);
        if (P == 0) {
          RD_AF(afB, (t + 1) % 3);
          if (t < 8) { RD_BF(bfB, t + 1, (io == 0 ? Bsm0 : Bsm1)); }
          else       { RD_BF(bfB, 0,     (io == 0 ? Bsm1 : Bsm0)); }
        } else {
          RD_AF(afA, (t + 1) % 3);
          if (t < 8) { RD_BF(bfA, t + 1, (io == 0 ? Bsm0 : Bsm1)); }
          else       { RD_BF(bfA, 0,     (io == 0 ? Bsm1 : Bsm0)); }
        }
      }

      // stage next icb's B into the shadow buffer, mid-icb (hidden)
      if (t == 4 && !(e == 14 && io == 1)) {
        stageB(icb + 1, (io == 0 ? Bsm1 : Bsm0));
        LGKM0();
        __builtin_amdgcn_sched_barrier(0);
      }
    }
  }

  // epilogue: scale by conv_scale*demod[b][oc], coalesced 64B stores
  const float* fsb = fscale + b * OC;
#pragma unroll
  for (int i = 0; i < 4; ++i) {
#pragma unroll
    for (int rr = 0; rr < 4; ++rr) {
      const int oc = mblk * 256 + wm * 64 + i * 16 + lk * 4 + rr;
      const float sc = fsb[oc];
      float* orow = out + ((size_t)(b * OC + oc)) * HW + nblk * 128 + wn * 64 + lrow;
#pragma unroll
      for (int j = 0; j < 4; ++j) orow[j * 16] = acc[i][j][rr] * sc;
    }
  }
}

// ---------------- launch --------------------------------------------------------
extern "C" void kernel_launch(void* const* d_in, const int* in_sizes, int n_in,
                              void* d_out, int out_size, void* d_ws, size_t ws_size,
                              hipStream_t stream) {
  const float* input = (const float*)d_in[0];       // [16,512,64,64]
  const float* style = (const float*)d_in[1];       // [16,512]
  const float* weight = (const float*)d_in[2];      // [1,512,512,3,3]
  const float* mod_weight = (const float*)d_in[3];  // [512,512]
  const float* mod_bias = (const float*)d_in[4];    // [512]
  float* out = (float*)d_out;

  char* ws = (char*)d_ws;
  constexpr size_t WPACK_B = (size_t)9 * OC * IC * 2;   // 4,718,592
  constexpr size_t W2SUM_B = (size_t)OC * IC * 4;       // 1,048,576
  constexpr size_t S_B = (size_t)BB * IC * 4;           // 32,768
  unsigned short* wpack = (unsigned short*)ws;
  float* w2sum = (float*)(ws + WPACK_B);
  float* s = (float*)(ws + WPACK_B + W2SUM_B);
  float* fscale = (float*)(ws + WPACK_B + W2SUM_B + S_B);

  constexpr int LDS_BYTES = (8 * 3 * 2048 + 2 * 8448) * 2;  // 132,096
  hipFuncSetAttribute((const void*)k_conv,
                      hipFuncAttributeMaxDynamicSharedMemorySize, LDS_BYTES);

  k_style<<<BB, 256, 0, stream>>>(style, mod_weight, mod_bias, s);
  k_pack<<<OC, 256, 0, stream>>>(weight, wpack, w2sum);
  k_demod<<<BB, 256, 0, stream>>>(s, w2sum, fscale);
  k_conv<<<1024, 512, LDS_BYTES, stream>>>(input, wpack, s, fscale, out);
}